// Round 2
// baseline (1260.323 us; speedup 1.0000x reference)
//
#include <hip/hip_runtime.h>
#include <math.h>

// out = softmax(s @ X[:-1]^T) @ X[1:]
//   X: (8192,1024) fp32, s: (8191,1024) fp32, out: (8191,1024) fp32
// R4: BQ=64, BK=256, 8 waves x (32 keys, 4 q-frags). Fragment-linear LDS Q/P
// (conflict-free, no pad), fragment-ordered coalesced K/V global layouts.

#define NQ 8191
#define NK 8191
#define DD 1024
#define BQ 64
#define BK 256
#define ITERS 32       // 8191/256 rounded up
#define NW 8
#define NT 512
#define QKK 31         // Q k-groups in LDS; group 31 lives in registers

typedef _Float16 half8 __attribute__((ext_vector_type(8)));
typedef float float4v __attribute__((ext_vector_type(4)));

// Kf[g=key/16][kk=d/32][lane][8]: lane l holds K[g*16+(l&15)][kk*32+(l>>4)*8+e]
__global__ void prep_kf(const float* __restrict__ X, _Float16* __restrict__ Kf) {
    int b = blockIdx.x * 256 + threadIdx.x;   // 1,048,576 half8 blocks
    int l  = b & 63;
    int kk = (b >> 6) & 31;
    int g  = b >> 11;                          // 0..511
    int row = g * 16 + (l & 15);               // 0..8191 (row 8191 masked in flash)
    int col = kk * 32 + ((l >> 4) << 3);
    const float4v* src = (const float4v*)&X[(size_t)row * DD + col];
    float4v v0 = src[0], v1 = src[1];
    half8 h;
    h[0]=(_Float16)v0[0]; h[1]=(_Float16)v0[1]; h[2]=(_Float16)v0[2]; h[3]=(_Float16)v0[3];
    h[4]=(_Float16)v1[0]; h[5]=(_Float16)v1[1]; h[6]=(_Float16)v1[2]; h[7]=(_Float16)v1[3];
    *(half8*)&Kf[(size_t)b * 8] = h;
}

// Vf[h=d/16][kkg=key/32][lane][8]: lane l holds V^T[h*16+(l&15)][kkg*32+(l>>4)*8+e]
// where V[key][d] = X[key+1][d]
__global__ void prep_vf(const float* __restrict__ X, _Float16* __restrict__ Vf) {
    int b = blockIdx.x * 256 + threadIdx.x;   // 1,048,576 half8 blocks
    int l   = b & 63;
    int kkg = (b >> 6) & 255;
    int h   = b >> 14;                         // 0..63
    int d    = h * 16 + (l & 15);
    int key0 = kkg * 32 + ((l >> 4) << 3);
    half8 hv;
    #pragma unroll
    for (int e = 0; e < 8; ++e) {
        int row = key0 + e + 1;
        float v = (row < 8192) ? X[(size_t)row * DD + d] : 0.f;
        hv[e] = (_Float16)v;
    }
    *(half8*)&Vf[(size_t)b * 8] = hv;
}

__launch_bounds__(NT, 2)
__global__ void flash(const float* __restrict__ s,
                      const _Float16* __restrict__ Kf,
                      const _Float16* __restrict__ Vf,
                      float* __restrict__ out) {
    __shared__ _Float16 Qf[4 * QKK * 64 * 8];   // 126,976 B, fragment-linear
    __shared__ _Float16 Pf[4 * 8 * 64 * 8];     // 32,768 B, fragment-linear
    __shared__ float    Rm[NW * BQ];            // 2 KB (reused as Rl in epilogue)

    const int t  = threadIdx.x;
    const int w  = t >> 6;       // wave 0..7
    const int l  = t & 63;
    const int ln = l & 15;
    const int q4 = l >> 4;
    const int q0 = blockIdx.x * BQ;

    // ---- stage Q: fragment-linear LDS (groups 0..30), group 31 in regs ----
    for (int e = t; e < 4 * QKK * 64; e += NT) {
        int ll  = e & 63;
        int rem = e >> 6;
        int kk  = rem % QKK;
        int qf  = rem / QKK;
        int row = qf * 16 + (ll & 15);
        int col = kk * 32 + ((ll >> 4) << 3);
        half8 hv;
        if (q0 + row < NQ) {
            const float4v* src = (const float4v*)&s[(size_t)(q0 + row) * DD + col];
            float4v v0 = src[0], v1 = src[1];
            hv[0]=(_Float16)v0[0]; hv[1]=(_Float16)v0[1]; hv[2]=(_Float16)v0[2]; hv[3]=(_Float16)v0[3];
            hv[4]=(_Float16)v1[0]; hv[5]=(_Float16)v1[1]; hv[6]=(_Float16)v1[2]; hv[7]=(_Float16)v1[3];
        } else {
            #pragma unroll
            for (int j = 0; j < 8; ++j) hv[j] = (_Float16)0.f;
        }
        *(half8*)&Qf[(size_t)e * 8] = hv;
    }
    half8 qreg[4];
    #pragma unroll
    for (int qf = 0; qf < 4; ++qf) {
        int row = qf * 16 + ln;
        int col = QKK * 32 + (q4 << 3);   // 992 + q4*8
        half8 hv;
        if (q0 + row < NQ) {
            const float4v* src = (const float4v*)&s[(size_t)(q0 + row) * DD + col];
            float4v v0 = src[0], v1 = src[1];
            hv[0]=(_Float16)v0[0]; hv[1]=(_Float16)v0[1]; hv[2]=(_Float16)v0[2]; hv[3]=(_Float16)v0[3];
            hv[4]=(_Float16)v1[0]; hv[5]=(_Float16)v1[1]; hv[6]=(_Float16)v1[2]; hv[7]=(_Float16)v1[3];
        } else {
            #pragma unroll
            for (int j = 0; j < 8; ++j) hv[j] = (_Float16)0.f;
        }
        qreg[qf] = hv;
    }
    __syncthreads();

    // O accumulator: wave w owns D chunk [w*128, w*128+128): 4 qf x 8 dt
    float4v o[4][8];
    #pragma unroll
    for (int qf = 0; qf < 4; ++qf)
        #pragma unroll
        for (int dt = 0; dt < 8; ++dt)
            o[qf][dt] = (float4v){0.f, 0.f, 0.f, 0.f};

    float m_run[16], l_run[16];
    #pragma unroll
    for (int i = 0; i < 16; ++i) { m_run[i] = -INFINITY; l_run[i] = 0.f; }

    // Pf write base (halfs): see layout derivation in comments below
    const int pbase = w * 512 + q4 * 32 + ((ln >> 3) << 7) + (ln & 7);

    for (int it = 0; it < ITERS; ++it) {
        // ---- phase 1: S[64 q][this wave's 32 keys], full-D contraction ----
        // Kf group base for this wave: g0 = it*16 + w*2 (+kf)
        const _Float16* kp0 = Kf + (size_t)(it * 16 + w * 2) * 16384 + (size_t)l * 8;
        float4v sa[4][2];
        #pragma unroll
        for (int qf = 0; qf < 4; ++qf) {
            sa[qf][0] = (float4v){0.f, 0.f, 0.f, 0.f};
            sa[qf][1] = (float4v){0.f, 0.f, 0.f, 0.f};
        }
        #pragma unroll 4
        for (int kk = 0; kk < QKK; ++kk) {
            half8 k0 = *(const half8*)(kp0 + kk * 512);
            half8 k1 = *(const half8*)(kp0 + 16384 + kk * 512);
            #pragma unroll
            for (int qf = 0; qf < 4; ++qf) {
                half8 qa = *(const half8*)&Qf[((qf * QKK + kk) * 64 + l) * 8];
                sa[qf][0] = __builtin_amdgcn_mfma_f32_16x16x32_f16(qa, k0, sa[qf][0], 0, 0, 0);
                sa[qf][1] = __builtin_amdgcn_mfma_f32_16x16x32_f16(qa, k1, sa[qf][1], 0, 0, 0);
            }
        }
        {   // k-group 31 from registers
            half8 k0 = *(const half8*)(kp0 + 31 * 512);
            half8 k1 = *(const half8*)(kp0 + 16384 + 31 * 512);
            #pragma unroll
            for (int qf = 0; qf < 4; ++qf) {
                sa[qf][0] = __builtin_amdgcn_mfma_f32_16x16x32_f16(qreg[qf], k0, sa[qf][0], 0, 0, 0);
                sa[qf][1] = __builtin_amdgcn_mfma_f32_16x16x32_f16(qreg[qf], k1, sa[qf][1], 0, 0, 0);
            }
        }

        const int kbase = it * BK + w * 32;
        const bool bad0 = (kbase + ln) >= NK;        // only key 8191 ever bad
        const bool bad1 = (kbase + 16 + ln) >= NK;

        // ---- wave-local row max over this wave's 32 keys ----
        float pm[16];
        #pragma unroll
        for (int qf = 0; qf < 4; ++qf)
            #pragma unroll
            for (int r = 0; r < 4; ++r) {
                float v0 = bad0 ? -INFINITY : sa[qf][0][r];
                float v1 = bad1 ? -INFINITY : sa[qf][1][r];
                pm[qf * 4 + r] = fmaxf(v0, v1);
            }
        #pragma unroll
        for (int i = 0; i < 16; ++i) {
            float v = pm[i];
            v = fmaxf(v, __shfl_xor(v, 1, 64));
            v = fmaxf(v, __shfl_xor(v, 2, 64));
            v = fmaxf(v, __shfl_xor(v, 4, 64));
            v = fmaxf(v, __shfl_xor(v, 8, 64));
            pm[i] = v;
        }
        if (ln == 0) {
            #pragma unroll
            for (int qf = 0; qf < 4; ++qf)
                #pragma unroll
                for (int r = 0; r < 4; ++r)
                    Rm[w * BQ + qf * 16 + q4 * 4 + r] = pm[qf * 4 + r];
        }
        __syncthreads();   // B: Rm visible

        // ---- global row max, alpha, P, l ----
        float al[16];
        #pragma unroll
        for (int qf = 0; qf < 4; ++qf)
            #pragma unroll
            for (int r = 0; r < 4; ++r) {
                int row = qf * 16 + q4 * 4 + r;
                int i = qf * 4 + r;
                float v = m_run[i];
                #pragma unroll
                for (int wv = 0; wv < NW; ++wv) v = fmaxf(v, Rm[wv * BQ + row]);
                al[i] = __expf(m_run[i] - v);
                m_run[i] = v;
            }
        #pragma unroll
        for (int i = 0; i < 16; ++i) l_run[i] *= al[i];
        // Pf element (row=qf*16+q4*4+r, key=w*32+kf*16+ln) at halfs:
        //   qf*4096 + w*512 + (q4*4+r)*8 + kf*256 + (ln>>3)*128 + (ln&7)
        #pragma unroll
        for (int qf = 0; qf < 4; ++qf)
            #pragma unroll
            for (int r = 0; r < 4; ++r) {
                int i = qf * 4 + r;
                float p0 = bad0 ? 0.f : __expf(sa[qf][0][r] - m_run[i]);
                float p1 = bad1 ? 0.f : __expf(sa[qf][1][r] - m_run[i]);
                l_run[i] += p0 + p1;
                Pf[pbase + qf * 4096 + r * 8]       = (_Float16)p0;
                Pf[pbase + qf * 4096 + r * 8 + 256] = (_Float16)p1;
            }
        // rescale O
        #pragma unroll
        for (int qf = 0; qf < 4; ++qf)
            #pragma unroll
            for (int dt = 0; dt < 8; ++dt)
                #pragma unroll
                for (int r = 0; r < 4; ++r)
                    o[qf][dt][r] *= al[qf * 4 + r];
        __syncthreads();   // D: Pf ready

        // ---- phase 3: O += P . V over all 256 keys, wave's 128-wide D ----
        const _Float16* vp = Vf + (size_t)(w * 8) * 131072 + (size_t)(it * 8) * 512 + (size_t)l * 8;
        #pragma unroll 2
        for (int kk2 = 0; kk2 < 8; ++kk2) {
            half8 pa[4];
            #pragma unroll
            for (int qf = 0; qf < 4; ++qf)
                pa[qf] = *(const half8*)&Pf[((qf * 8 + kk2) * 64 + l) * 8];
            #pragma unroll
            for (int dt = 0; dt < 8; ++dt) {
                half8 vf = *(const half8*)(vp + (size_t)dt * 131072 + kk2 * 512);
                #pragma unroll
                for (int qf = 0; qf < 4; ++qf)
                    o[qf][dt] = __builtin_amdgcn_mfma_f32_16x16x32_f16(pa[qf], vf, o[qf][dt], 0, 0, 0);
            }
        }
        __syncthreads();   // A: Pf/Rm free for next iter
    }

    // ---- epilogue: reduce l across lanes and waves, scale, store ----
    float lt[16];
    #pragma unroll
    for (int i = 0; i < 16; ++i) {
        float v = l_run[i];
        v += __shfl_xor(v, 1, 64);
        v += __shfl_xor(v, 2, 64);
        v += __shfl_xor(v, 4, 64);
        v += __shfl_xor(v, 8, 64);
        lt[i] = v;
    }
    if (ln == 0) {
        #pragma unroll
        for (int qf = 0; qf < 4; ++qf)
            #pragma unroll
            for (int r = 0; r < 4; ++r)
                Rm[w * BQ + qf * 16 + q4 * 4 + r] = lt[qf * 4 + r];
    }
    __syncthreads();

    float inv[16];
    #pragma unroll
    for (int qf = 0; qf < 4; ++qf)
        #pragma unroll
        for (int r = 0; r < 4; ++r) {
            int row = qf * 16 + q4 * 4 + r;
            float sum = 0.f;
            #pragma unroll
            for (int wv = 0; wv < NW; ++wv) sum += Rm[wv * BQ + row];
            inv[qf * 4 + r] = 1.f / sum;
        }

    #pragma unroll
    for (int qf = 0; qf < 4; ++qf)
        #pragma unroll
        for (int dt = 0; dt < 8; ++dt)
            #pragma unroll
            for (int r = 0; r < 4; ++r) {
                int row = q0 + qf * 16 + q4 * 4 + r;
                int col = w * 128 + dt * 16 + ln;
                if (row < NQ)
                    out[(size_t)row * DD + col] = o[qf][dt][r] * inv[qf * 4 + r];
            }
}

extern "C" void kernel_launch(void* const* d_in, const int* in_sizes, int n_in,
                              void* d_out, int out_size, void* d_ws, size_t ws_size,
                              hipStream_t stream) {
    const float* X = (const float*)d_in[0];
    const float* s = (const float*)d_in[1];
    float* out = (float*)d_out;

    _Float16* Kf = (_Float16*)d_ws;                 // 16 MiB
    _Float16* Vf = Kf + (size_t)8192 * 1024;        // 16 MiB

    prep_kf<<<4096, 256, 0, stream>>>(X, Kf);
    prep_vf<<<4096, 256, 0, stream>>>(X, Vf);
    flash<<<(NQ + BQ - 1) / BQ, NT, 0, stream>>>(s, Kf, Vf, out);
}

// Round 3
// 683.782 us; speedup vs baseline: 1.8432x; 1.8432x over previous
//
#include <hip/hip_runtime.h>
#include <math.h>

// out = softmax(s @ X[:-1]^T) @ X[1:]
//   X: (8192,1024) fp32, s: (8191,1024) fp32, out: (8191,1024) fp32
// R5: BQ=64, key-split=2 (grid 256 = 128 q-tiles x 2 key-halves), BK=256,
// 8 waves x (32 keys, 4 q-frags). Fragment-linear LDS Q/P, fragment-ordered
// coalesced K/V. Partial O (fp16, normalized) + (m,l) to ws; combine kernel.

#define NQ 8191
#define NK 8191
#define DD 1024
#define BQ 64
#define BK 256
#define KSPLIT 2
#define KHALF 4096     // keys per split
#define ITERS 16       // 4096/256
#define NW 8
#define NT 512
#define QKK 31         // Q k-groups in LDS; group 31 lives in registers

typedef _Float16 half8 __attribute__((ext_vector_type(8)));
typedef float float4v __attribute__((ext_vector_type(4)));

// Kf[g=key/16][kk=d/32][lane][8]: lane l holds K[g*16+(l&15)][kk*32+(l>>4)*8+e]
__global__ void prep_kf(const float* __restrict__ X, _Float16* __restrict__ Kf) {
    int b = blockIdx.x * 256 + threadIdx.x;   // 1,048,576 half8 blocks
    int l  = b & 63;
    int kk = (b >> 6) & 31;
    int g  = b >> 11;                          // 0..511
    int row = g * 16 + (l & 15);               // 0..8191 (row 8191 masked in flash)
    int col = kk * 32 + ((l >> 4) << 3);
    const float4v* src = (const float4v*)&X[(size_t)row * DD + col];
    float4v v0 = src[0], v1 = src[1];
    half8 h;
    h[0]=(_Float16)v0[0]; h[1]=(_Float16)v0[1]; h[2]=(_Float16)v0[2]; h[3]=(_Float16)v0[3];
    h[4]=(_Float16)v1[0]; h[5]=(_Float16)v1[1]; h[6]=(_Float16)v1[2]; h[7]=(_Float16)v1[3];
    *(half8*)&Kf[(size_t)b * 8] = h;
}

// Vf[h=d/16][kkg=key/32][lane][8]: lane l holds V^T[h*16+(l&15)][kkg*32+(l>>4)*8+e]
// where V[key][d] = X[key+1][d]
__global__ void prep_vf(const float* __restrict__ X, _Float16* __restrict__ Vf) {
    int b = blockIdx.x * 256 + threadIdx.x;   // 1,048,576 half8 blocks
    int l   = b & 63;
    int kkg = (b >> 6) & 255;
    int h   = b >> 14;                         // 0..63
    int d    = h * 16 + (l & 15);
    int key0 = kkg * 32 + ((l >> 4) << 3);
    half8 hv;
    #pragma unroll
    for (int e = 0; e < 8; ++e) {
        int row = key0 + e + 1;
        float v = (row < 8192) ? X[(size_t)row * DD + d] : 0.f;
        hv[e] = (_Float16)v;
    }
    *(half8*)&Vf[(size_t)b * 8] = hv;
}

__launch_bounds__(NT, 2)
__global__ void flash(const float* __restrict__ s,
                      const _Float16* __restrict__ Kf,
                      const _Float16* __restrict__ Vf,
                      _Float16* __restrict__ Op,
                      float2* __restrict__ ml) {
    __shared__ _Float16 Qf[4 * QKK * 64 * 8];   // 126,976 B, fragment-linear
    __shared__ _Float16 Pf[4 * 8 * 64 * 8];     // 32,768 B, fragment-linear
    __shared__ float    Rm[NW * BQ];            // 2 KB (reused as Rl in epilogue)

    const int t  = threadIdx.x;
    const int w  = t >> 6;       // wave 0..7
    const int l  = t & 63;
    const int ln = l & 15;
    const int q4 = l >> 4;
    const int qt = blockIdx.x >> 1;
    const int ks = blockIdx.x & 1;
    const int q0 = qt * BQ;

    // ---- stage Q: fragment-linear LDS (groups 0..30), group 31 in regs ----
    for (int e = t; e < 4 * QKK * 64; e += NT) {
        int ll  = e & 63;
        int rem = e >> 6;
        int kk  = rem % QKK;
        int qf  = rem / QKK;
        int row = qf * 16 + (ll & 15);
        int col = kk * 32 + ((ll >> 4) << 3);
        half8 hv;
        if (q0 + row < NQ) {
            const float4v* src = (const float4v*)&s[(size_t)(q0 + row) * DD + col];
            float4v v0 = src[0], v1 = src[1];
            hv[0]=(_Float16)v0[0]; hv[1]=(_Float16)v0[1]; hv[2]=(_Float16)v0[2]; hv[3]=(_Float16)v0[3];
            hv[4]=(_Float16)v1[0]; hv[5]=(_Float16)v1[1]; hv[6]=(_Float16)v1[2]; hv[7]=(_Float16)v1[3];
        } else {
            #pragma unroll
            for (int j = 0; j < 8; ++j) hv[j] = (_Float16)0.f;
        }
        *(half8*)&Qf[(size_t)e * 8] = hv;
    }
    half8 qreg[4];
    #pragma unroll
    for (int qf = 0; qf < 4; ++qf) {
        int row = qf * 16 + ln;
        int col = QKK * 32 + (q4 << 3);   // 992 + q4*8
        half8 hv;
        if (q0 + row < NQ) {
            const float4v* src = (const float4v*)&s[(size_t)(q0 + row) * DD + col];
            float4v v0 = src[0], v1 = src[1];
            hv[0]=(_Float16)v0[0]; hv[1]=(_Float16)v0[1]; hv[2]=(_Float16)v0[2]; hv[3]=(_Float16)v0[3];
            hv[4]=(_Float16)v1[0]; hv[5]=(_Float16)v1[1]; hv[6]=(_Float16)v1[2]; hv[7]=(_Float16)v1[3];
        } else {
            #pragma unroll
            for (int j = 0; j < 8; ++j) hv[j] = (_Float16)0.f;
        }
        qreg[qf] = hv;
    }
    __syncthreads();

    // O accumulator: wave w owns D chunk [w*128, w*128+128): 4 qf x 8 dt
    float4v o[4][8];
    #pragma unroll
    for (int qf = 0; qf < 4; ++qf)
        #pragma unroll
        for (int dt = 0; dt < 8; ++dt)
            o[qf][dt] = (float4v){0.f, 0.f, 0.f, 0.f};

    float m_run[16], l_run[16];
    #pragma unroll
    for (int i = 0; i < 16; ++i) { m_run[i] = -INFINITY; l_run[i] = 0.f; }

    const int pbase = w * 512 + q4 * 32 + ((ln >> 3) << 7) + (ln & 7);

    for (int it = 0; it < ITERS; ++it) {
        // ---- phase 1: S[64 q][this wave's 32 keys], full-D contraction ----
        const _Float16* kp0 = Kf + (size_t)(ks * 256 + it * 16 + w * 2) * 16384 + (size_t)l * 8;
        float4v sa[4][2];
        #pragma unroll
        for (int qf = 0; qf < 4; ++qf) {
            sa[qf][0] = (float4v){0.f, 0.f, 0.f, 0.f};
            sa[qf][1] = (float4v){0.f, 0.f, 0.f, 0.f};
        }
        #pragma unroll 4
        for (int kk = 0; kk < QKK; ++kk) {
            half8 k0 = *(const half8*)(kp0 + kk * 512);
            half8 k1 = *(const half8*)(kp0 + 16384 + kk * 512);
            #pragma unroll
            for (int qf = 0; qf < 4; ++qf) {
                half8 qa = *(const half8*)&Qf[((qf * QKK + kk) * 64 + l) * 8];
                sa[qf][0] = __builtin_amdgcn_mfma_f32_16x16x32_f16(qa, k0, sa[qf][0], 0, 0, 0);
                sa[qf][1] = __builtin_amdgcn_mfma_f32_16x16x32_f16(qa, k1, sa[qf][1], 0, 0, 0);
            }
        }
        {   // k-group 31 from registers
            half8 k0 = *(const half8*)(kp0 + 31 * 512);
            half8 k1 = *(const half8*)(kp0 + 16384 + 31 * 512);
            #pragma unroll
            for (int qf = 0; qf < 4; ++qf) {
                sa[qf][0] = __builtin_amdgcn_mfma_f32_16x16x32_f16(qreg[qf], k0, sa[qf][0], 0, 0, 0);
                sa[qf][1] = __builtin_amdgcn_mfma_f32_16x16x32_f16(qreg[qf], k1, sa[qf][1], 0, 0, 0);
            }
        }

        const int kbase = ks * KHALF + it * BK + w * 32;
        const bool bad0 = (kbase + ln) >= NK;        // only key 8191 ever bad
        const bool bad1 = (kbase + 16 + ln) >= NK;

        // ---- wave-local row max over this wave's 32 keys ----
        float pm[16];
        #pragma unroll
        for (int qf = 0; qf < 4; ++qf)
            #pragma unroll
            for (int r = 0; r < 4; ++r) {
                float v0 = bad0 ? -INFINITY : sa[qf][0][r];
                float v1 = bad1 ? -INFINITY : sa[qf][1][r];
                pm[qf * 4 + r] = fmaxf(v0, v1);
            }
        #pragma unroll
        for (int i = 0; i < 16; ++i) {
            float v = pm[i];
            v = fmaxf(v, __shfl_xor(v, 1, 64));
            v = fmaxf(v, __shfl_xor(v, 2, 64));
            v = fmaxf(v, __shfl_xor(v, 4, 64));
            v = fmaxf(v, __shfl_xor(v, 8, 64));
            pm[i] = v;
        }
        if (ln == 0) {
            #pragma unroll
            for (int qf = 0; qf < 4; ++qf)
                #pragma unroll
                for (int r = 0; r < 4; ++r)
                    Rm[w * BQ + qf * 16 + q4 * 4 + r] = pm[qf * 4 + r];
        }
        __syncthreads();   // B: Rm visible

        // ---- global row max, alpha, P, l ----
        float al[16];
        #pragma unroll
        for (int qf = 0; qf < 4; ++qf)
            #pragma unroll
            for (int r = 0; r < 4; ++r) {
                int row = qf * 16 + q4 * 4 + r;
                int i = qf * 4 + r;
                float v = m_run[i];
                #pragma unroll
                for (int wv = 0; wv < NW; ++wv) v = fmaxf(v, Rm[wv * BQ + row]);
                al[i] = __expf(m_run[i] - v);
                m_run[i] = v;
            }
        #pragma unroll
        for (int i = 0; i < 16; ++i) l_run[i] *= al[i];
        #pragma unroll
        for (int qf = 0; qf < 4; ++qf)
            #pragma unroll
            for (int r = 0; r < 4; ++r) {
                int i = qf * 4 + r;
                float p0 = bad0 ? 0.f : __expf(sa[qf][0][r] - m_run[i]);
                float p1 = bad1 ? 0.f : __expf(sa[qf][1][r] - m_run[i]);
                l_run[i] += p0 + p1;
                Pf[pbase + qf * 4096 + r * 8]       = (_Float16)p0;
                Pf[pbase + qf * 4096 + r * 8 + 256] = (_Float16)p1;
            }
        // rescale O
        #pragma unroll
        for (int qf = 0; qf < 4; ++qf)
            #pragma unroll
            for (int dt = 0; dt < 8; ++dt)
                #pragma unroll
                for (int r = 0; r < 4; ++r)
                    o[qf][dt][r] *= al[qf * 4 + r];
        __syncthreads();   // D: Pf ready

        // ---- phase 3: O += P . V over all 256 keys, wave's 128-wide D ----
        const _Float16* vp = Vf + (size_t)(w * 8) * 131072
                             + (size_t)(ks * 128 + it * 8) * 512 + (size_t)l * 8;
        #pragma unroll 2
        for (int kk2 = 0; kk2 < 8; ++kk2) {
            half8 pa[4];
            #pragma unroll
            for (int qf = 0; qf < 4; ++qf)
                pa[qf] = *(const half8*)&Pf[((qf * 8 + kk2) * 64 + l) * 8];
            #pragma unroll
            for (int dt = 0; dt < 8; ++dt) {
                half8 vf = *(const half8*)(vp + (size_t)dt * 131072 + kk2 * 512);
                #pragma unroll
                for (int qf = 0; qf < 4; ++qf)
                    o[qf][dt] = __builtin_amdgcn_mfma_f32_16x16x32_f16(pa[qf], vf, o[qf][dt], 0, 0, 0);
            }
        }
        __syncthreads();   // A: Pf/Rm free for next iter
    }

    // ---- epilogue: reduce l across lanes and waves, store partials ----
    float lt[16];
    #pragma unroll
    for (int i = 0; i < 16; ++i) {
        float v = l_run[i];
        v += __shfl_xor(v, 1, 64);
        v += __shfl_xor(v, 2, 64);
        v += __shfl_xor(v, 4, 64);
        v += __shfl_xor(v, 8, 64);
        lt[i] = v;
    }
    if (ln == 0) {
        #pragma unroll
        for (int qf = 0; qf < 4; ++qf)
            #pragma unroll
            for (int r = 0; r < 4; ++r)
                Rm[w * BQ + qf * 16 + q4 * 4 + r] = lt[qf * 4 + r];
    }
    __syncthreads();

    float lsum[16], inv[16];
    #pragma unroll
    for (int qf = 0; qf < 4; ++qf)
        #pragma unroll
        for (int r = 0; r < 4; ++r) {
            int row = qf * 16 + q4 * 4 + r;
            float sum = 0.f;
            #pragma unroll
            for (int wv = 0; wv < NW; ++wv) sum += Rm[wv * BQ + row];
            lsum[qf * 4 + r] = sum;
            inv[qf * 4 + r] = 1.f / sum;
        }

    if (w == 0 && ln == 0) {
        #pragma unroll
        for (int qf = 0; qf < 4; ++qf)
            #pragma unroll
            for (int r = 0; r < 4; ++r) {
                int row = q0 + qf * 16 + q4 * 4 + r;
                int i = qf * 4 + r;
                if (row < NQ)
                    ml[ks * 8192 + row] = make_float2(m_run[i], lsum[i]);
            }
    }

    #pragma unroll
    for (int qf = 0; qf < 4; ++qf)
        #pragma unroll
        for (int dt = 0; dt < 8; ++dt)
            #pragma unroll
            for (int r = 0; r < 4; ++r) {
                int row = q0 + qf * 16 + q4 * 4 + r;
                int col = w * 128 + dt * 16 + ln;
                if (row < NQ)
                    Op[((size_t)ks * NQ + row) * DD + col] =
                        (_Float16)(o[qf][dt][r] * inv[qf * 4 + r]);
            }
}

// out = w0 * Op[0] + w1 * Op[1], weights from (m,l) pairs
__global__ void combine(const _Float16* __restrict__ Op,
                        const float2* __restrict__ ml,
                        float* __restrict__ out) {
    size_t idx = ((size_t)blockIdx.x * 256 + threadIdx.x) * 8;
    if (idx >= (size_t)NQ * DD) return;
    int row = (int)(idx >> 10);
    float2 a = ml[row];
    float2 b = ml[8192 + row];
    float m  = fmaxf(a.x, b.x);
    float w0 = a.y * __expf(a.x - m);
    float w1 = b.y * __expf(b.x - m);
    float inv = 1.f / (w0 + w1);
    w0 *= inv; w1 *= inv;
    half8 h0 = *(const half8*)&Op[idx];
    half8 h1 = *(const half8*)&Op[(size_t)NQ * DD + idx];
    float4v o0, o1;
    #pragma unroll
    for (int e = 0; e < 4; ++e) o0[e] = w0 * (float)h0[e] + w1 * (float)h1[e];
    #pragma unroll
    for (int e = 0; e < 4; ++e) o1[e] = w0 * (float)h0[e + 4] + w1 * (float)h1[e + 4];
    *(float4v*)&out[idx]     = o0;
    *(float4v*)&out[idx + 4] = o1;
}

extern "C" void kernel_launch(void* const* d_in, const int* in_sizes, int n_in,
                              void* d_out, int out_size, void* d_ws, size_t ws_size,
                              hipStream_t stream) {
    const float* X = (const float*)d_in[0];
    const float* s = (const float*)d_in[1];
    float* out = (float*)d_out;

    _Float16* Kf = (_Float16*)d_ws;                  // 16 MiB
    _Float16* Vf = Kf + (size_t)8192 * 1024;         // 16 MiB
    _Float16* Op = Vf + (size_t)8192 * 1024;         // 32 MiB (2 x NQ x DD fp16)
    float2*   ml = (float2*)(Op + (size_t)2 * NQ * DD);  // 128 KiB

    prep_kf<<<4096, 256, 0, stream>>>(X, Kf);
    prep_vf<<<4096, 256, 0, stream>>>(X, Vf);
    flash<<<KSPLIT * ((NQ + BQ - 1) / BQ), NT, 0, stream>>>(s, Kf, Vf, Op, ml);
    combine<<<4096, 256, 0, stream>>>(Op, ml, out);
}

// Round 4
// 664.708 us; speedup vs baseline: 1.8961x; 1.0287x over previous
//
#include <hip/hip_runtime.h>
#include <math.h>

// out = softmax(s @ X[:-1]^T) @ X[1:]
//   X: (8192,1024) fp32, s: (8191,1024) fp32, out: (8191,1024) fp32
// R6: R5 structure (BQ=64, KSPLIT=2, BK=256, 8 waves x 32 keys) +
//  - register ping-pong prefetch for K (8 chunks of 4 kk) and V (per kk2)
//  - cross-phase pipelining (V chunk 0 loads during phase 1 tail; next-iter
//    K chunk 0 loads during phase 3 tail)
//  - XCD-pure key-half assignment (all CUs on an XCD stream the same half)
//  - Rm transposed to [row][wave] for float4 cross-wave reductions

#define NQ 8191
#define NK 8191
#define DD 1024
#define BQ 64
#define BK 256
#define KSPLIT 2
#define KHALF 4096
#define ITERS 16
#define NW 8
#define NT 512
#define QKK 31         // Q k-groups in LDS; group 31 lives in registers

typedef _Float16 half8 __attribute__((ext_vector_type(8)));
typedef float float4v __attribute__((ext_vector_type(4)));

// Kf[g=key/16][kk=d/32][lane][8]: lane l holds K[g*16+(l&15)][kk*32+(l>>4)*8+e]
__global__ void prep_kf(const float* __restrict__ X, _Float16* __restrict__ Kf) {
    int b = blockIdx.x * 256 + threadIdx.x;
    int l  = b & 63;
    int kk = (b >> 6) & 31;
    int g  = b >> 11;
    int row = g * 16 + (l & 15);
    int col = kk * 32 + ((l >> 4) << 3);
    const float4v* src = (const float4v*)&X[(size_t)row * DD + col];
    float4v v0 = src[0], v1 = src[1];
    half8 h;
    h[0]=(_Float16)v0[0]; h[1]=(_Float16)v0[1]; h[2]=(_Float16)v0[2]; h[3]=(_Float16)v0[3];
    h[4]=(_Float16)v1[0]; h[5]=(_Float16)v1[1]; h[6]=(_Float16)v1[2]; h[7]=(_Float16)v1[3];
    *(half8*)&Kf[(size_t)b * 8] = h;
}

// Vf[h=d/16][kkg=key/32][lane][8]: lane l holds V^T[h*16+(l&15)][kkg*32+(l>>4)*8+e]
__global__ void prep_vf(const float* __restrict__ X, _Float16* __restrict__ Vf) {
    int b = blockIdx.x * 256 + threadIdx.x;
    int l   = b & 63;
    int kkg = (b >> 6) & 255;
    int h   = b >> 14;
    int d    = h * 16 + (l & 15);
    int key0 = kkg * 32 + ((l >> 4) << 3);
    half8 hv;
    #pragma unroll
    for (int e = 0; e < 8; ++e) {
        int row = key0 + e + 1;
        float v = (row < 8192) ? X[(size_t)row * DD + d] : 0.f;
        hv[e] = (_Float16)v;
    }
    *(half8*)&Vf[(size_t)b * 8] = hv;
}

#define LOADK(BUF, KKBASE)                                                    \
    _Pragma("unroll")                                                         \
    for (int j = 0; j < 4; ++j) {                                             \
        BUF[j][0] = *(const half8*)(kp0 + (KKBASE + j) * 512);                \
        BUF[j][1] = *(const half8*)(kp0 + 16384 + (KKBASE + j) * 512);        \
    }

#define MFMAK(BUF, KKBASE)                                                    \
    _Pragma("unroll")                                                         \
    for (int j = 0; j < 4; ++j) {                                             \
        _Pragma("unroll")                                                     \
        for (int qf = 0; qf < 4; ++qf) {                                      \
            half8 qa = ((KKBASE + j) == 31) ? qreg[qf]                        \
                 : *(const half8*)&Qf[((qf * QKK + (KKBASE + j)) * 64 + l) * 8]; \
            sa[qf][0] = __builtin_amdgcn_mfma_f32_16x16x32_f16(qa, BUF[j][0], sa[qf][0], 0, 0, 0); \
            sa[qf][1] = __builtin_amdgcn_mfma_f32_16x16x32_f16(qa, BUF[j][1], sa[qf][1], 0, 0, 0); \
        }                                                                     \
    }

#define LOADV(BUF, KK2)                                                       \
    _Pragma("unroll")                                                         \
    for (int dt = 0; dt < 8; ++dt)                                            \
        BUF[dt] = *(const half8*)(vp + (size_t)dt * 131072 + (KK2) * 512);

#define MFMAV(BUF, KK2)                                                       \
    {                                                                         \
        half8 pa[4];                                                          \
        _Pragma("unroll")                                                     \
        for (int qf = 0; qf < 4; ++qf)                                        \
            pa[qf] = *(const half8*)&Pf[((qf * 8 + (KK2)) * 64 + l) * 8];     \
        _Pragma("unroll")                                                     \
        for (int dt = 0; dt < 8; ++dt)                                        \
            _Pragma("unroll")                                                 \
            for (int qf = 0; qf < 4; ++qf)                                    \
                o[qf][dt] = __builtin_amdgcn_mfma_f32_16x16x32_f16(pa[qf], BUF[dt], o[qf][dt], 0, 0, 0); \
    }

__launch_bounds__(NT, 2)
__global__ void flash(const float* __restrict__ s,
                      const _Float16* __restrict__ Kf,
                      const _Float16* __restrict__ Vf,
                      _Float16* __restrict__ Op,
                      float2* __restrict__ ml) {
    __shared__ _Float16 Qf[4 * QKK * 64 * 8];   // 126,976 B, fragment-linear
    __shared__ _Float16 Pf[4 * 8 * 64 * 8];     // 32,768 B, fragment-linear
    __shared__ float    Rm[BQ * NW];            // [row][wave], 2 KB

    const int t  = threadIdx.x;
    const int w  = t >> 6;
    const int l  = t & 63;
    const int ln = l & 15;
    const int q4 = l >> 4;

    // XCD-pure mapping: xcd = bid%8 (round-robin); all blocks on one XCD
    // stream the same key half; qt spread across XCD pairs.
    const int bid  = blockIdx.x;
    const int xcd  = bid & 7;
    const int slot = bid >> 3;
    const int ks   = xcd & 1;
    const int qt   = slot * 4 + (xcd >> 1);
    const int q0   = qt * BQ;

    // ---- stage Q: fragment-linear LDS (groups 0..30), group 31 in regs ----
    for (int e = t; e < 4 * QKK * 64; e += NT) {
        int ll  = e & 63;
        int rem = e >> 6;
        int kk  = rem % QKK;
        int qf  = rem / QKK;
        int row = qf * 16 + (ll & 15);
        int col = kk * 32 + ((ll >> 4) << 3);
        half8 hv;
        if (q0 + row < NQ) {
            const float4v* src = (const float4v*)&s[(size_t)(q0 + row) * DD + col];
            float4v v0 = src[0], v1 = src[1];
            hv[0]=(_Float16)v0[0]; hv[1]=(_Float16)v0[1]; hv[2]=(_Float16)v0[2]; hv[3]=(_Float16)v0[3];
            hv[4]=(_Float16)v1[0]; hv[5]=(_Float16)v1[1]; hv[6]=(_Float16)v1[2]; hv[7]=(_Float16)v1[3];
        } else {
            #pragma unroll
            for (int j = 0; j < 8; ++j) hv[j] = (_Float16)0.f;
        }
        *(half8*)&Qf[(size_t)e * 8] = hv;
    }
    half8 qreg[4];
    #pragma unroll
    for (int qf = 0; qf < 4; ++qf) {
        int row = qf * 16 + ln;
        int col = QKK * 32 + (q4 << 3);
        half8 hv;
        if (q0 + row < NQ) {
            const float4v* src = (const float4v*)&s[(size_t)(q0 + row) * DD + col];
            float4v v0 = src[0], v1 = src[1];
            hv[0]=(_Float16)v0[0]; hv[1]=(_Float16)v0[1]; hv[2]=(_Float16)v0[2]; hv[3]=(_Float16)v0[3];
            hv[4]=(_Float16)v1[0]; hv[5]=(_Float16)v1[1]; hv[6]=(_Float16)v1[2]; hv[7]=(_Float16)v1[3];
        } else {
            #pragma unroll
            for (int j = 0; j < 8; ++j) hv[j] = (_Float16)0.f;
        }
        qreg[qf] = hv;
    }
    __syncthreads();

    float4v o[4][8];
    #pragma unroll
    for (int qf = 0; qf < 4; ++qf)
        #pragma unroll
        for (int dt = 0; dt < 8; ++dt)
            o[qf][dt] = (float4v){0.f, 0.f, 0.f, 0.f};

    float m_run[16], l_run[16];
    #pragma unroll
    for (int i = 0; i < 16; ++i) { m_run[i] = -INFINITY; l_run[i] = 0.f; }

    const int pbase = w * 512 + q4 * 32 + ((ln >> 3) << 7) + (ln & 7);

    half8 kA[4][2], kB[4][2];   // K ping-pong (4 k-groups each)
    half8 vA[8], vB[8];         // V ping-pong (8 d-tiles each)

    // prologue: load iter-0 K chunk 0 into kA
    {
        const _Float16* kp0 = Kf + (size_t)(ks * 256 + w * 2) * 16384 + (size_t)l * 8;
        LOADK(kA, 0);
    }

    for (int it = 0; it < ITERS; ++it) {
        const _Float16* kp0 = Kf + (size_t)(ks * 256 + it * 16 + w * 2) * 16384 + (size_t)l * 8;
        const _Float16* vp  = Vf + (size_t)(w * 8) * 131072
                              + (size_t)(ks * 128 + it * 8) * 512 + (size_t)l * 8;

        // ---- phase 1: S[64 q][wave's 32 keys], chunked with prefetch ----
        float4v sa[4][2];
        #pragma unroll
        for (int qf = 0; qf < 4; ++qf) {
            sa[qf][0] = (float4v){0.f, 0.f, 0.f, 0.f};
            sa[qf][1] = (float4v){0.f, 0.f, 0.f, 0.f};
        }
        LOADK(kB, 4);   MFMAK(kA, 0);
        LOADK(kA, 8);   MFMAK(kB, 4);
        LOADK(kB, 12);  MFMAK(kA, 8);
        LOADK(kA, 16);  MFMAK(kB, 12);
        LOADK(kB, 20);  MFMAK(kA, 16);
        LOADK(kA, 24);  MFMAK(kB, 20);
        LOADK(kB, 28);  MFMAK(kA, 24);
        LOADV(vA, 0);   MFMAK(kB, 28);   // V kk2=0 flies over softmax

        const int kbase = ks * KHALF + it * BK + w * 32;
        const bool bad0 = (kbase + ln) >= NK;
        const bool bad1 = (kbase + 16 + ln) >= NK;

        // ---- wave-local row max ----
        float pm[16];
        #pragma unroll
        for (int qf = 0; qf < 4; ++qf)
            #pragma unroll
            for (int r = 0; r < 4; ++r) {
                float v0 = bad0 ? -INFINITY : sa[qf][0][r];
                float v1 = bad1 ? -INFINITY : sa[qf][1][r];
                pm[qf * 4 + r] = fmaxf(v0, v1);
            }
        #pragma unroll
        for (int i = 0; i < 16; ++i) {
            float v = pm[i];
            v = fmaxf(v, __shfl_xor(v, 1, 64));
            v = fmaxf(v, __shfl_xor(v, 2, 64));
            v = fmaxf(v, __shfl_xor(v, 4, 64));
            v = fmaxf(v, __shfl_xor(v, 8, 64));
            pm[i] = v;
        }
        if (ln == 0) {
            #pragma unroll
            for (int qf = 0; qf < 4; ++qf)
                #pragma unroll
                for (int r = 0; r < 4; ++r)
                    Rm[(qf * 16 + q4 * 4 + r) * NW + w] = pm[qf * 4 + r];
        }
        __syncthreads();   // B: Rm visible

        // ---- global row max, alpha, P, l ----
        float al[16];
        #pragma unroll
        for (int qf = 0; qf < 4; ++qf)
            #pragma unroll
            for (int r = 0; r < 4; ++r) {
                int row = qf * 16 + q4 * 4 + r;
                int i = qf * 4 + r;
                float4v ra = *(const float4v*)&Rm[row * NW];
                float4v rb = *(const float4v*)&Rm[row * NW + 4];
                float v = fmaxf(fmaxf(fmaxf(ra[0], ra[1]), fmaxf(ra[2], ra[3])),
                                fmaxf(fmaxf(rb[0], rb[1]), fmaxf(rb[2], rb[3])));
                v = fmaxf(v, m_run[i]);
                al[i] = __expf(m_run[i] - v);
                m_run[i] = v;
            }
        #pragma unroll
        for (int i = 0; i < 16; ++i) l_run[i] *= al[i];
        #pragma unroll
        for (int qf = 0; qf < 4; ++qf)
            #pragma unroll
            for (int r = 0; r < 4; ++r) {
                int i = qf * 4 + r;
                float p0 = bad0 ? 0.f : __expf(sa[qf][0][r] - m_run[i]);
                float p1 = bad1 ? 0.f : __expf(sa[qf][1][r] - m_run[i]);
                l_run[i] += p0 + p1;
                Pf[pbase + qf * 4096 + r * 8]       = (_Float16)p0;
                Pf[pbase + qf * 4096 + r * 8 + 256] = (_Float16)p1;
            }
        #pragma unroll
        for (int qf = 0; qf < 4; ++qf)
            #pragma unroll
            for (int dt = 0; dt < 8; ++dt)
                #pragma unroll
                for (int r = 0; r < 4; ++r)
                    o[qf][dt][r] *= al[qf * 4 + r];
        __syncthreads();   // D: Pf ready

        // ---- phase 3: O += P . V, chunked with prefetch ----
        LOADV(vB, 1);  MFMAV(vA, 0);
        LOADV(vA, 2);  MFMAV(vB, 1);
        LOADV(vB, 3);  MFMAV(vA, 2);
        LOADV(vA, 4);  MFMAV(vB, 3);
        LOADV(vB, 5);  MFMAV(vA, 4);
        LOADV(vA, 6);  MFMAV(vB, 5);
        LOADV(vB, 7);  MFMAV(vA, 6);
        {   // next-iter K chunk 0 flies over barrier A
            int itn = (it + 1) & (ITERS - 1);
            const _Float16* kpn = Kf + (size_t)(ks * 256 + itn * 16 + w * 2) * 16384
                                  + (size_t)l * 8;
            #pragma unroll
            for (int j = 0; j < 4; ++j) {
                kA[j][0] = *(const half8*)(kpn + j * 512);
                kA[j][1] = *(const half8*)(kpn + 16384 + j * 512);
            }
        }
        MFMAV(vB, 7);
        __syncthreads();   // A: Pf/Rm free for next iter
    }

    // ---- epilogue: reduce l across lanes and waves, store partials ----
    float lt[16];
    #pragma unroll
    for (int i = 0; i < 16; ++i) {
        float v = l_run[i];
        v += __shfl_xor(v, 1, 64);
        v += __shfl_xor(v, 2, 64);
        v += __shfl_xor(v, 4, 64);
        v += __shfl_xor(v, 8, 64);
        lt[i] = v;
    }
    if (ln == 0) {
        #pragma unroll
        for (int qf = 0; qf < 4; ++qf)
            #pragma unroll
            for (int r = 0; r < 4; ++r)
                Rm[(qf * 16 + q4 * 4 + r) * NW + w] = lt[qf * 4 + r];
    }
    __syncthreads();

    float lsum[16], inv[16];
    #pragma unroll
    for (int qf = 0; qf < 4; ++qf)
        #pragma unroll
        for (int r = 0; r < 4; ++r) {
            int row = qf * 16 + q4 * 4 + r;
            float4v ra = *(const float4v*)&Rm[row * NW];
            float4v rb = *(const float4v*)&Rm[row * NW + 4];
            float sum = (ra[0] + ra[1] + ra[2] + ra[3])
                      + (rb[0] + rb[1] + rb[2] + rb[3]);
            lsum[qf * 4 + r] = sum;
            inv[qf * 4 + r] = 1.f / sum;
        }

    if (w == 0 && ln == 0) {
        #pragma unroll
        for (int qf = 0; qf < 4; ++qf)
            #pragma unroll
            for (int r = 0; r < 4; ++r) {
                int row = q0 + qf * 16 + q4 * 4 + r;
                int i = qf * 4 + r;
                if (row < NQ)
                    ml[ks * 8192 + row] = make_float2(m_run[i], lsum[i]);
            }
    }

    #pragma unroll
    for (int qf = 0; qf < 4; ++qf)
        #pragma unroll
        for (int dt = 0; dt < 8; ++dt)
            #pragma unroll
            for (int r = 0; r < 4; ++r) {
                int row = q0 + qf * 16 + q4 * 4 + r;
                int col = w * 128 + dt * 16 + ln;
                if (row < NQ)
                    Op[((size_t)ks * NQ + row) * DD + col] =
                        (_Float16)(o[qf][dt][r] * inv[qf * 4 + r]);
            }
}

// out = w0 * Op[0] + w1 * Op[1], weights from (m,l) pairs
__global__ void combine(const _Float16* __restrict__ Op,
                        const float2* __restrict__ ml,
                        float* __restrict__ out) {
    size_t idx = ((size_t)blockIdx.x * 256 + threadIdx.x) * 8;
    if (idx >= (size_t)NQ * DD) return;
    int row = (int)(idx >> 10);
    float2 a = ml[row];
    float2 b = ml[8192 + row];
    float m  = fmaxf(a.x, b.x);
    float w0 = a.y * __expf(a.x - m);
    float w1 = b.y * __expf(b.x - m);
    float inv = 1.f / (w0 + w1);
    w0 *= inv; w1 *= inv;
    half8 h0 = *(const half8*)&Op[idx];
    half8 h1 = *(const half8*)&Op[(size_t)NQ * DD + idx];
    float4v o0, o1;
    #pragma unroll
    for (int e = 0; e < 4; ++e) o0[e] = w0 * (float)h0[e] + w1 * (float)h1[e];
    #pragma unroll
    for (int e = 0; e < 4; ++e) o1[e] = w0 * (float)h0[e + 4] + w1 * (float)h1[e + 4];
    *(float4v*)&out[idx]     = o0;
    *(float4v*)&out[idx + 4] = o1;
}

extern "C" void kernel_launch(void* const* d_in, const int* in_sizes, int n_in,
                              void* d_out, int out_size, void* d_ws, size_t ws_size,
                              hipStream_t stream) {
    const float* X = (const float*)d_in[0];
    const float* s = (const float*)d_in[1];
    float* out = (float*)d_out;

    _Float16* Kf = (_Float16*)d_ws;                  // 16 MiB
    _Float16* Vf = Kf + (size_t)8192 * 1024;         // 16 MiB
    _Float16* Op = Vf + (size_t)8192 * 1024;         // 32 MiB
    float2*   ml = (float2*)(Op + (size_t)2 * NQ * DD);  // 128 KiB

    prep_kf<<<4096, 256, 0, stream>>>(X, Kf);
    prep_vf<<<4096, 256, 0, stream>>>(X, Vf);
    flash<<<KSPLIT * ((NQ + BQ - 1) / BQ), NT, 0, stream>>>(s, Kf, Vf, Op, ml);
    combine<<<4096, 256, 0, stream>>>(Op, ml, out);
}